// Round 10
// baseline (587.537 us; speedup 1.0000x reference)
//
#include <hip/hip_runtime.h>
#include <hip/hip_bf16.h>
#include <cstdint>

#define NN 8192
#define EE 128
#define AA 8
#define QSCALE 0.08838834764831845f   // 1/sqrt(128)
#define KVW 8                          // waves per block = KV partitions
#define KVLEN (NN / KVW)               // 1024 cols per wave
#define NIT (KVLEN / 64)               // 16 chunks per wave
#define NW (NN / 64)                   // 128 mask words per row

typedef __attribute__((ext_vector_type(8))) short bf16x8;
typedef __attribute__((ext_vector_type(4))) float f32x4;
typedef unsigned short u16;
typedef unsigned int u32;
typedef unsigned long long u64;

__device__ __forceinline__ u16 bf16_bits(float x) {
    union { float f; u32 u; } v; v.f = x;
    u32 r = v.u + 0x7fffu + ((v.u >> 16) & 1u);   // RNE
    return (u16)(r >> 16);
}

// ---------------------------------------------------------------------------
// Kernel 0: pack adj (int32 {0,1}, 256MB) into a bitmask (8MB).
// ---------------------------------------------------------------------------
__global__ __launch_bounds__(256) void k_adjmask(
    const int* __restrict__ adj, u64* __restrict__ msk)
{
    const u32 gwave  = (blockIdx.x * 256 + threadIdx.x) >> 6;
    const u32 nwaves = (gridDim.x * 256) >> 6;
    const int lane   = threadIdx.x & 63;
    const size_t nwords = (size_t)NN * NW;   // 1,048,576
    for (size_t w = (size_t)gwave * 4; w < nwords; w += (size_t)nwaves * 4) {
        u64 b[4];
        #pragma unroll
        for (int u = 0; u < 4; ++u)
            b[u] = __ballot(adj[(w + u) * 64 + lane] != 0);
        if (lane == 0) {
            *reinterpret_cast<ulonglong2*>(&msk[w])     = ulonglong2{b[0], b[1]};
            *reinterpret_cast<ulonglong2*>(&msk[w + 2]) = ulonglong2{b[2], b[3]};
        }
    }
}

// ---------------------------------------------------------------------------
// Kernel 1: h = relu(state@w1+b1)@w2+b2 ; q = (h@wq)/sqrt(E) ; k = h@wk
// Writes q,k as bf16 [N][E] and hT as bf16 [E][N].
// ---------------------------------------------------------------------------
__global__ __launch_bounds__(128) void k_mlp(
    const float* __restrict__ state,
    const float* __restrict__ w1, const float* __restrict__ b1,
    const float* __restrict__ w2, const float* __restrict__ b2,
    const float* __restrict__ wq, const float* __restrict__ wk,
    u16* __restrict__ qb, u16* __restrict__ kb, u16* __restrict__ hT)
{
    __shared__ float st[16][EE + 1];   // state tile, then reused for h
    __shared__ float h1[16][EE + 1];
    const int t  = threadIdx.x;
    const int rg = t >> 4;            // 0..7
    const int ec = (t & 15) * 8;      // col base
    const int ra = rg * 2, rb = ra + 1;
    const int r0b = blockIdx.x * 16;

    #pragma unroll
    for (int r = 0; r < 16; ++r)
        st[r][t] = state[(size_t)(r0b + r) * EE + t];
    __syncthreads();

    // stage 1: h1 = relu(st@w1 + b1)
    {
        float a0[8], a1[8];
        #pragma unroll
        for (int j = 0; j < 8; ++j) { float b = b1[ec + j]; a0[j] = b; a1[j] = b; }
        for (int s = 0; s < EE; ++s) {
            float x0 = st[ra][s], x1 = st[rb][s];
            const float* wrow = w1 + s * EE + ec;
            #pragma unroll
            for (int j = 0; j < 8; ++j) { float w = wrow[j]; a0[j] = fmaf(x0, w, a0[j]); a1[j] = fmaf(x1, w, a1[j]); }
        }
        __syncthreads();
        #pragma unroll
        for (int j = 0; j < 8; ++j) { h1[ra][ec + j] = fmaxf(a0[j], 0.f); h1[rb][ec + j] = fmaxf(a1[j], 0.f); }
    }
    __syncthreads();

    // stage 2: h = h1@w2 + b2
    float hva[8], hvb[8];
    {
        float a0[8], a1[8];
        #pragma unroll
        for (int j = 0; j < 8; ++j) { float b = b2[ec + j]; a0[j] = b; a1[j] = b; }
        for (int s = 0; s < EE; ++s) {
            float x0 = h1[ra][s], x1 = h1[rb][s];
            const float* wrow = w2 + s * EE + ec;
            #pragma unroll
            for (int j = 0; j < 8; ++j) { float w = wrow[j]; a0[j] = fmaf(x0, w, a0[j]); a1[j] = fmaf(x1, w, a1[j]); }
        }
        #pragma unroll
        for (int j = 0; j < 8; ++j) {
            st[ra][ec + j] = a0[j]; st[rb][ec + j] = a1[j];
            hva[j] = a0[j]; hvb[j] = a1[j];
        }
    }
    __syncthreads();

    // stage 3: q = (h@wq)*QSCALE, k = h@wk
    {
        float q0[8], q1[8], k0[8], k1[8];
        #pragma unroll
        for (int j = 0; j < 8; ++j) { q0[j] = 0.f; q1[j] = 0.f; k0[j] = 0.f; k1[j] = 0.f; }
        for (int s = 0; s < EE; ++s) {
            float x0 = st[ra][s], x1 = st[rb][s];
            const float* wqr = wq + s * EE + ec;
            const float* wkr = wk + s * EE + ec;
            #pragma unroll
            for (int j = 0; j < 8; ++j) {
                float a = wqr[j], b = wkr[j];
                q0[j] = fmaf(x0, a, q0[j]); q1[j] = fmaf(x1, a, q1[j]);
                k0[j] = fmaf(x0, b, k0[j]); k1[j] = fmaf(x1, b, k1[j]);
            }
        }
        bf16x8 vq0, vq1, vk0, vk1;
        #pragma unroll
        for (int j = 0; j < 8; ++j) {
            vq0[j] = (short)bf16_bits(q0[j] * QSCALE);
            vq1[j] = (short)bf16_bits(q1[j] * QSCALE);
            vk0[j] = (short)bf16_bits(k0[j]);
            vk1[j] = (short)bf16_bits(k1[j]);
        }
        *reinterpret_cast<bf16x8*>(qb + (size_t)(r0b + ra) * EE + ec) = vq0;
        *reinterpret_cast<bf16x8*>(qb + (size_t)(r0b + rb) * EE + ec) = vq1;
        *reinterpret_cast<bf16x8*>(kb + (size_t)(r0b + ra) * EE + ec) = vk0;
        *reinterpret_cast<bf16x8*>(kb + (size_t)(r0b + rb) * EE + ec) = vk1;
    }

    #pragma unroll
    for (int j = 0; j < 8; ++j) {
        u32 pack = (u32)bf16_bits(hva[j]) | ((u32)bf16_bits(hvb[j]) << 16);
        *reinterpret_cast<u32*>(hT + (size_t)(ec + j) * NN + r0b + ra) = pack;
    }
}

// ---------------------------------------------------------------------------
// Kernel 2: flash-style masked attention with block-level KV split.
// Round-6 structure (measured 256us) with ONE lever: fp16 partial-combine
// LDS (64KB -> 32KB) => 4 blocks/CU = 32 waves/CU (~100% occupancy).
// __launch_bounds__(512,8) pins VGPR<=64. Second sched_barrier dropped.
// ---------------------------------------------------------------------------
__global__ __launch_bounds__(512, 8) void k_attn(
    const u16* __restrict__ qb, const u16* __restrict__ kb,
    const u16* __restrict__ hT, const u64* __restrict__ msk,
    float* __restrict__ agg)
{
    __shared__ _Float16 lds_acc[KVW][16][EE];  // 32 KB; first 2KB of each
                                               // wave's 4KB slot = its P tile
    __shared__ float lds_m[KVW][16];
    __shared__ float lds_l[KVW][16];

    const int tid  = threadIdx.x;
    const int wv   = tid >> 6;
    const int lane = tid & 63;
    const int l15  = lane & 15;
    const int g    = lane >> 4;
    const int qbase = blockIdx.x * 16;
    const int kv0   = wv * KVLEN;

    // Q fragments stay in registers for the whole kernel
    bf16x8 qf[4];
    #pragma unroll
    for (int ks = 0; ks < 4; ++ks)
        qf[ks] = *reinterpret_cast<const bf16x8*>(qb + (size_t)(qbase + l15) * EE + ks * 32 + g * 8);

    f32x4 acc[8];
    #pragma unroll
    for (int et = 0; et < 8; ++et) acc[et] = f32x4{0.f, 0.f, 0.f, 0.f};
    float m[4], l[4];
    #pragma unroll
    for (int j = 0; j < 4; ++j) { m[j] = -__builtin_inff(); l[j] = 0.f; }

    const u64* mbase = msk + (size_t)(qbase + g * 4) * NW + (kv0 >> 6);
    u16* plw = reinterpret_cast<u16*>(&lds_acc[wv][0][0]);   // [16][64] swizzled

    for (int cc = 0; cc < NIT; ++cc) {
        const int c0 = kv0 + cc * 64;
        // mask words for this wave's 4 row-groups (broadcast loads, L2-hot)
        u64 mw[4];
        #pragma unroll
        for (int j = 0; j < 4; ++j)
            mw[j] = mbase[(size_t)j * NW + cc];

        // S = q @ k^T  (pre-scaled q)
        f32x4 sv[4];
        #pragma unroll
        for (int nt = 0; nt < 4; ++nt) sv[nt] = f32x4{0.f, 0.f, 0.f, 0.f};
        #pragma unroll
        for (int nt = 0; nt < 4; ++nt) {
            #pragma unroll
            for (int ks = 0; ks < 4; ++ks) {
                bf16x8 bk = *reinterpret_cast<const bf16x8*>(
                    kb + (size_t)(c0 + nt * 16 + l15) * EE + ks * 32 + g * 8);
                sv[nt] = __builtin_amdgcn_mfma_f32_16x16x32_bf16(qf[ks], bk, sv[nt], 0, 0, 0);
            }
        }
        // adjacency mask via bit test
        float ms[4][4];
        #pragma unroll
        for (int nt = 0; nt < 4; ++nt)
            #pragma unroll
            for (int j = 0; j < 4; ++j)
                ms[nt][j] = ((mw[j] >> (nt * 16 + l15)) & 1ull) ? sv[nt][j]
                                                                : -__builtin_inff();

        // online softmax over this 64-col chunk
        float alpha[4], mn[4];
        #pragma unroll
        for (int j = 0; j < 4; ++j) {
            float rm = fmaxf(fmaxf(ms[0][j], ms[1][j]), fmaxf(ms[2][j], ms[3][j]));
            rm = fmaxf(rm, __shfl_xor(rm, 1));
            rm = fmaxf(rm, __shfl_xor(rm, 2));
            rm = fmaxf(rm, __shfl_xor(rm, 4));
            rm = fmaxf(rm, __shfl_xor(rm, 8));
            mn[j] = fmaxf(m[j], rm);
            alpha[j] = (mn[j] == m[j]) ? 1.f : __expf(m[j] - mn[j]);
            m[j] = mn[j];
        }
        float rs[4] = {0.f, 0.f, 0.f, 0.f};
        u16 pb[4][4];
        #pragma unroll
        for (int nt = 0; nt < 4; ++nt) {
            #pragma unroll
            for (int j = 0; j < 4; ++j) {
                float pv = (mn[j] == -__builtin_inff()) ? 0.f : __expf(ms[nt][j] - mn[j]);
                rs[j] += pv;
                pb[nt][j] = bf16_bits(pv);
            }
        }
        #pragma unroll
        for (int j = 0; j < 4; ++j) {
            float r = rs[j];
            r += __shfl_xor(r, 1);
            r += __shfl_xor(r, 2);
            r += __shfl_xor(r, 4);
            r += __shfl_xor(r, 8);
            l[j] = l[j] * alpha[j] + r;
        }
        // P (D-layout) -> per-wave LDS tile -> A-frag layout (XOR swizzle)
        #pragma unroll
        for (int nt = 0; nt < 4; ++nt) {
            #pragma unroll
            for (int j = 0; j < 4; ++j) {
                int row = g * 4 + j;
                int col = nt * 16 + l15;
                plw[row * 64 + (col ^ ((row & 7) << 3))] = pb[nt][j];
            }
        }
        asm volatile("s_waitcnt lgkmcnt(0)" ::: "memory");
        __builtin_amdgcn_sched_barrier(0);
        bf16x8 pa[2];
        #pragma unroll
        for (int ks = 0; ks < 2; ++ks) {
            int eo = (ks * 32 + g * 8) ^ ((l15 & 7) << 3);
            pa[ks] = *reinterpret_cast<const bf16x8*>(&plw[l15 * 64 + eo]);
        }
        // rescale + PV:  acc += P @ h_chunk   (B-frags contiguous via hT)
        f32x4 avv = {alpha[0], alpha[1], alpha[2], alpha[3]};
        #pragma unroll
        for (int et = 0; et < 8; ++et) {
            acc[et] = acc[et] * avv;
            #pragma unroll
            for (int ks = 0; ks < 2; ++ks) {
                bf16x8 bh = *reinterpret_cast<const bf16x8*>(
                    hT + (size_t)(et * 16 + l15) * NN + c0 + ks * 32 + g * 8);
                acc[et] = __builtin_amdgcn_mfma_f32_16x16x32_bf16(pa[ks], bh, acc[et], 0, 0, 0);
            }
        }
    }

    // write partials as fp16 (overwrites this wave's P region -- wave-local)
    #pragma unroll
    for (int et = 0; et < 8; ++et)
        #pragma unroll
        for (int j = 0; j < 4; ++j)
            lds_acc[wv][g * 4 + j][et * 16 + l15] = (_Float16)acc[et][j];
    if (l15 == 0) {
        #pragma unroll
        for (int j = 0; j < 4; ++j) {
            lds_m[wv][g * 4 + j] = m[j];
            lds_l[wv][g * 4 + j] = l[j];
        }
    }
    __syncthreads();

    // combine 8 partials: wave wv owns rows {2wv, 2wv+1}; lane owns 2 cols
    #pragma unroll
    for (int rr = 0; rr < 2; ++rr) {
        const int r = wv * 2 + rr;
        float mp[KVW], M = -__builtin_inff();
        #pragma unroll
        for (int p = 0; p < KVW; ++p) { mp[p] = lds_m[p][r]; M = fmaxf(M, mp[p]); }
        float ep[KVW], L = 0.f;
        #pragma unroll
        for (int p = 0; p < KVW; ++p) { ep[p] = __expf(mp[p] - M); L += lds_l[p][r] * ep[p]; }
        const float invL = 1.f / L;
        #pragma unroll
        for (int cs = 0; cs < 2; ++cs) {
            const int c = lane + cs * 64;
            float s = 0.f;
            #pragma unroll
            for (int p = 0; p < KVW; ++p) s += (float)lds_acc[p][r][c] * ep[p];
            agg[(size_t)(qbase + r) * EE + c] = s * invL;
        }
    }
}

// ---------------------------------------------------------------------------
// Kernel 3: out = relu(agg@wh1+bh1)@wh2 + bh2
// ---------------------------------------------------------------------------
__global__ __launch_bounds__(128) void k_head(
    const float* __restrict__ agg,
    const float* __restrict__ wh1, const float* __restrict__ bh1,
    const float* __restrict__ wh2, const float* __restrict__ bh2,
    float* __restrict__ out)
{
    __shared__ float ag[16][EE + 1];
    __shared__ float h2[16][EE + 1];
    const int t  = threadIdx.x;
    const int rg = t >> 4;
    const int ec = (t & 15) * 8;
    const int ra = rg * 2, rb = ra + 1;
    const int r0b = blockIdx.x * 16;

    #pragma unroll
    for (int r = 0; r < 16; ++r)
        ag[r][t] = agg[(size_t)(r0b + r) * EE + t];
    __syncthreads();
    {
        float a0[8], a1[8];
        #pragma unroll
        for (int j = 0; j < 8; ++j) { float b = bh1[ec + j]; a0[j] = b; a1[j] = b; }
        for (int s = 0; s < EE; ++s) {
            float x0 = ag[ra][s], x1 = ag[rb][s];
            const float* wrow = wh1 + s * EE + ec;
            #pragma unroll
            for (int j = 0; j < 8; ++j) { float w = wrow[j]; a0[j] = fmaf(x0, w, a0[j]); a1[j] = fmaf(x1, w, a1[j]); }
        }
        #pragma unroll
        for (int j = 0; j < 8; ++j) { h2[ra][ec + j] = fmaxf(a0[j], 0.f); h2[rb][ec + j] = fmaxf(a1[j], 0.f); }
    }
    __syncthreads();
    const int r = t >> 3, a = t & 7;
    float o = bh2[a];
    for (int s = 0; s < EE; ++s) o = fmaf(h2[r][s], wh2[s * AA + a], o);
    out[(size_t)(r0b + r) * AA + a] = o;
}

// ---------------------------------------------------------------------------
extern "C" void kernel_launch(void* const* d_in, const int* in_sizes, int n_in,
                              void* d_out, int out_size, void* d_ws, size_t ws_size,
                              hipStream_t stream)
{
    (void)in_sizes; (void)n_in; (void)out_size; (void)ws_size;
    const float* state = (const float*)d_in[0];
    const int*   adj   = (const int*)d_in[1];
    const float* w1  = (const float*)d_in[2];
    const float* b1  = (const float*)d_in[3];
    const float* w2  = (const float*)d_in[4];
    const float* b2  = (const float*)d_in[5];
    const float* wq  = (const float*)d_in[6];
    const float* wk  = (const float*)d_in[7];
    const float* wh1 = (const float*)d_in[8];
    const float* bh1 = (const float*)d_in[9];
    const float* wh2 = (const float*)d_in[10];
    const float* bh2 = (const float*)d_in[11];
    float* out = (float*)d_out;

    char* ws = (char*)d_ws;
    u16*  qb  = (u16*)ws;                                  //  0..2 MB
    u16*  kb  = (u16*)(ws + (size_t)NN * EE * 2);          //  2..4 MB
    u16*  hT  = (u16*)(ws + (size_t)NN * EE * 4);          //  4..6 MB
    float* agg = (float*)(ws + (size_t)NN * EE * 6);       //  6..10 MB
    u64*  msk = (u64*)(ws + (size_t)NN * EE * 6 + (size_t)NN * EE * 4); // 10..18 MB

    k_mlp    <<<NN / 16, 128, 0, stream>>>(state, w1, b1, w2, b2, wq, wk, qb, kb, hT);
    k_adjmask<<<2048, 256, 0, stream>>>(adj, msk);
    k_attn   <<<NN / 16, 512, 0, stream>>>(qb, kb, hT, msk, agg);
    k_head   <<<NN / 16, 128, 0, stream>>>(agg, wh1, bh1, wh2, bh2, out);
}

// Round 12
// 352.541 us; speedup vs baseline: 1.6666x; 1.6666x over previous
//
#include <hip/hip_runtime.h>
#include <hip/hip_bf16.h>
#include <cstdint>

#define NN 8192
#define EE 128
#define AA 8
#define QSCALE 0.08838834764831845f   // 1/sqrt(128)
#define KVW 8                          // waves per block = KV partitions
#define KVLEN (NN / KVW)               // 1024 cols per wave
#define NIT (KVLEN / 64)               // 16 chunks per wave
#define NW (NN / 64)                   // 128 mask words per row

typedef __attribute__((ext_vector_type(8))) short bf16x8;
typedef __attribute__((ext_vector_type(4))) float f32x4;
typedef unsigned short u16;
typedef unsigned int u32;
typedef unsigned long long u64;

__device__ __forceinline__ u16 bf16_bits(float x) {
    union { float f; u32 u; } v; v.f = x;
    u32 r = v.u + 0x7fffu + ((v.u >> 16) & 1u);   // RNE
    return (u16)(r >> 16);
}

// ---------------------------------------------------------------------------
// Kernel 0: pack adj (int32 {0,1}, 256MB) into a bitmask (8MB).
// ---------------------------------------------------------------------------
__global__ __launch_bounds__(256) void k_adjmask(
    const int* __restrict__ adj, u64* __restrict__ msk)
{
    const u32 gwave  = (blockIdx.x * 256 + threadIdx.x) >> 6;
    const u32 nwaves = (gridDim.x * 256) >> 6;
    const int lane   = threadIdx.x & 63;
    const size_t nwords = (size_t)NN * NW;   // 1,048,576
    for (size_t w = (size_t)gwave * 4; w < nwords; w += (size_t)nwaves * 4) {
        u64 b[4];
        #pragma unroll
        for (int u = 0; u < 4; ++u)
            b[u] = __ballot(adj[(w + u) * 64 + lane] != 0);
        if (lane == 0) {
            *reinterpret_cast<ulonglong2*>(&msk[w])     = ulonglong2{b[0], b[1]};
            *reinterpret_cast<ulonglong2*>(&msk[w + 2]) = ulonglong2{b[2], b[3]};
        }
    }
}

// ---------------------------------------------------------------------------
// Kernel 1: h = relu(state@w1+b1)@w2+b2 ; q = (h@wq)/sqrt(E) ; k = h@wk
// Writes q,k as bf16 [N][E] and hT as bf16 [E][N].
// ---------------------------------------------------------------------------
__global__ __launch_bounds__(128) void k_mlp(
    const float* __restrict__ state,
    const float* __restrict__ w1, const float* __restrict__ b1,
    const float* __restrict__ w2, const float* __restrict__ b2,
    const float* __restrict__ wq, const float* __restrict__ wk,
    u16* __restrict__ qb, u16* __restrict__ kb, u16* __restrict__ hT)
{
    __shared__ float st[16][EE + 1];   // state tile, then reused for h
    __shared__ float h1[16][EE + 1];
    const int t  = threadIdx.x;
    const int rg = t >> 4;            // 0..7
    const int ec = (t & 15) * 8;      // col base
    const int ra = rg * 2, rb = ra + 1;
    const int r0b = blockIdx.x * 16;

    #pragma unroll
    for (int r = 0; r < 16; ++r)
        st[r][t] = state[(size_t)(r0b + r) * EE + t];
    __syncthreads();

    // stage 1: h1 = relu(st@w1 + b1)
    {
        float a0[8], a1[8];
        #pragma unroll
        for (int j = 0; j < 8; ++j) { float b = b1[ec + j]; a0[j] = b; a1[j] = b; }
        for (int s = 0; s < EE; ++s) {
            float x0 = st[ra][s], x1 = st[rb][s];
            const float* wrow = w1 + s * EE + ec;
            #pragma unroll
            for (int j = 0; j < 8; ++j) { float w = wrow[j]; a0[j] = fmaf(x0, w, a0[j]); a1[j] = fmaf(x1, w, a1[j]); }
        }
        __syncthreads();
        #pragma unroll
        for (int j = 0; j < 8; ++j) { h1[ra][ec + j] = fmaxf(a0[j], 0.f); h1[rb][ec + j] = fmaxf(a1[j], 0.f); }
    }
    __syncthreads();

    // stage 2: h = h1@w2 + b2
    float hva[8], hvb[8];
    {
        float a0[8], a1[8];
        #pragma unroll
        for (int j = 0; j < 8; ++j) { float b = b2[ec + j]; a0[j] = b; a1[j] = b; }
        for (int s = 0; s < EE; ++s) {
            float x0 = h1[ra][s], x1 = h1[rb][s];
            const float* wrow = w2 + s * EE + ec;
            #pragma unroll
            for (int j = 0; j < 8; ++j) { float w = wrow[j]; a0[j] = fmaf(x0, w, a0[j]); a1[j] = fmaf(x1, w, a1[j]); }
        }
        #pragma unroll
        for (int j = 0; j < 8; ++j) {
            st[ra][ec + j] = a0[j]; st[rb][ec + j] = a1[j];
            hva[j] = a0[j]; hvb[j] = a1[j];
        }
    }
    __syncthreads();

    // stage 3: q = (h@wq)*QSCALE, k = h@wk
    {
        float q0[8], q1[8], k0[8], k1[8];
        #pragma unroll
        for (int j = 0; j < 8; ++j) { q0[j] = 0.f; q1[j] = 0.f; k0[j] = 0.f; k1[j] = 0.f; }
        for (int s = 0; s < EE; ++s) {
            float x0 = st[ra][s], x1 = st[rb][s];
            const float* wqr = wq + s * EE + ec;
            const float* wkr = wk + s * EE + ec;
            #pragma unroll
            for (int j = 0; j < 8; ++j) {
                float a = wqr[j], b = wkr[j];
                q0[j] = fmaf(x0, a, q0[j]); q1[j] = fmaf(x1, a, q1[j]);
                k0[j] = fmaf(x0, b, k0[j]); k1[j] = fmaf(x1, b, k1[j]);
            }
        }
        bf16x8 vq0, vq1, vk0, vk1;
        #pragma unroll
        for (int j = 0; j < 8; ++j) {
            vq0[j] = (short)bf16_bits(q0[j] * QSCALE);
            vq1[j] = (short)bf16_bits(q1[j] * QSCALE);
            vk0[j] = (short)bf16_bits(k0[j]);
            vk1[j] = (short)bf16_bits(k1[j]);
        }
        *reinterpret_cast<bf16x8*>(qb + (size_t)(r0b + ra) * EE + ec) = vq0;
        *reinterpret_cast<bf16x8*>(qb + (size_t)(r0b + rb) * EE + ec) = vq1;
        *reinterpret_cast<bf16x8*>(kb + (size_t)(r0b + ra) * EE + ec) = vk0;
        *reinterpret_cast<bf16x8*>(kb + (size_t)(r0b + rb) * EE + ec) = vk1;
    }

    #pragma unroll
    for (int j = 0; j < 8; ++j) {
        u32 pack = (u32)bf16_bits(hva[j]) | ((u32)bf16_bits(hvb[j]) << 16);
        *reinterpret_cast<u32*>(hT + (size_t)(ec + j) * NN + r0b + ra) = pack;
    }
}

// ---------------------------------------------------------------------------
// Kernel 2: flash-style masked attention with block-level KV split.
// Round-6 structure + fp16 partial-combine LDS (64KB -> 33KB => 4 blocks/CU).
// launch_bounds (512,4): natural VGPR=64 (measured R4-R9, no spill), which
// permits 32 waves/CU. DO NOT raise min-waves to 8: it forces VGPR=32 and
// spills 1.28GB to scratch (measured R10, 463us).
// ---------------------------------------------------------------------------
__global__ __launch_bounds__(512, 4) void k_attn(
    const u16* __restrict__ qb, const u16* __restrict__ kb,
    const u16* __restrict__ hT, const u64* __restrict__ msk,
    float* __restrict__ agg)
{
    __shared__ _Float16 lds_acc[KVW][16][EE];  // 32 KB; first 2KB of each
                                               // wave's 4KB slot = its P tile
    __shared__ float lds_m[KVW][16];
    __shared__ float lds_l[KVW][16];

    const int tid  = threadIdx.x;
    const int wv   = tid >> 6;
    const int lane = tid & 63;
    const int l15  = lane & 15;
    const int g    = lane >> 4;
    const int qbase = blockIdx.x * 16;
    const int kv0   = wv * KVLEN;

    // Q fragments stay in registers for the whole kernel
    bf16x8 qf[4];
    #pragma unroll
    for (int ks = 0; ks < 4; ++ks)
        qf[ks] = *reinterpret_cast<const bf16x8*>(qb + (size_t)(qbase + l15) * EE + ks * 32 + g * 8);

    f32x4 acc[8];
    #pragma unroll
    for (int et = 0; et < 8; ++et) acc[et] = f32x4{0.f, 0.f, 0.f, 0.f};
    float m[4], l[4];
    #pragma unroll
    for (int j = 0; j < 4; ++j) { m[j] = -__builtin_inff(); l[j] = 0.f; }

    const u64* mbase = msk + (size_t)(qbase + g * 4) * NW + (kv0 >> 6);
    u16* plw = reinterpret_cast<u16*>(&lds_acc[wv][0][0]);   // [16][64] swizzled

    for (int cc = 0; cc < NIT; ++cc) {
        const int c0 = kv0 + cc * 64;
        // mask words for this wave's 4 row-groups (broadcast loads, L2-hot)
        u64 mw[4];
        #pragma unroll
        for (int j = 0; j < 4; ++j)
            mw[j] = mbase[(size_t)j * NW + cc];

        // S = q @ k^T  (pre-scaled q)
        f32x4 sv[4];
        #pragma unroll
        for (int nt = 0; nt < 4; ++nt) sv[nt] = f32x4{0.f, 0.f, 0.f, 0.f};
        #pragma unroll
        for (int nt = 0; nt < 4; ++nt) {
            #pragma unroll
            for (int ks = 0; ks < 4; ++ks) {
                bf16x8 bk = *reinterpret_cast<const bf16x8*>(
                    kb + (size_t)(c0 + nt * 16 + l15) * EE + ks * 32 + g * 8);
                sv[nt] = __builtin_amdgcn_mfma_f32_16x16x32_bf16(qf[ks], bk, sv[nt], 0, 0, 0);
            }
        }
        // adjacency mask via bit test
        float ms[4][4];
        #pragma unroll
        for (int nt = 0; nt < 4; ++nt)
            #pragma unroll
            for (int j = 0; j < 4; ++j)
                ms[nt][j] = ((mw[j] >> (nt * 16 + l15)) & 1ull) ? sv[nt][j]
                                                                : -__builtin_inff();

        // online softmax over this 64-col chunk
        float alpha[4], mn[4];
        #pragma unroll
        for (int j = 0; j < 4; ++j) {
            float rm = fmaxf(fmaxf(ms[0][j], ms[1][j]), fmaxf(ms[2][j], ms[3][j]));
            rm = fmaxf(rm, __shfl_xor(rm, 1));
            rm = fmaxf(rm, __shfl_xor(rm, 2));
            rm = fmaxf(rm, __shfl_xor(rm, 4));
            rm = fmaxf(rm, __shfl_xor(rm, 8));
            mn[j] = fmaxf(m[j], rm);
            alpha[j] = (mn[j] == m[j]) ? 1.f : __expf(m[j] - mn[j]);
            m[j] = mn[j];
        }
        float rs[4] = {0.f, 0.f, 0.f, 0.f};
        u16 pb[4][4];
        #pragma unroll
        for (int nt = 0; nt < 4; ++nt) {
            #pragma unroll
            for (int j = 0; j < 4; ++j) {
                float pv = (mn[j] == -__builtin_inff()) ? 0.f : __expf(ms[nt][j] - mn[j]);
                rs[j] += pv;
                pb[nt][j] = bf16_bits(pv);
            }
        }
        #pragma unroll
        for (int j = 0; j < 4; ++j) {
            float r = rs[j];
            r += __shfl_xor(r, 1);
            r += __shfl_xor(r, 2);
            r += __shfl_xor(r, 4);
            r += __shfl_xor(r, 8);
            l[j] = l[j] * alpha[j] + r;
        }
        // P (D-layout) -> per-wave LDS tile -> A-frag layout (XOR swizzle)
        #pragma unroll
        for (int nt = 0; nt < 4; ++nt) {
            #pragma unroll
            for (int j = 0; j < 4; ++j) {
                int row = g * 4 + j;
                int col = nt * 16 + l15;
                plw[row * 64 + (col ^ ((row & 7) << 3))] = pb[nt][j];
            }
        }
        asm volatile("s_waitcnt lgkmcnt(0)" ::: "memory");
        __builtin_amdgcn_sched_barrier(0);
        bf16x8 pa[2];
        #pragma unroll
        for (int ks = 0; ks < 2; ++ks) {
            int eo = (ks * 32 + g * 8) ^ ((l15 & 7) << 3);
            pa[ks] = *reinterpret_cast<const bf16x8*>(&plw[l15 * 64 + eo]);
        }
        // rescale + PV:  acc += P @ h_chunk   (B-frags contiguous via hT)
        f32x4 avv = {alpha[0], alpha[1], alpha[2], alpha[3]};
        #pragma unroll
        for (int et = 0; et < 8; ++et) {
            acc[et] = acc[et] * avv;
            #pragma unroll
            for (int ks = 0; ks < 2; ++ks) {
                bf16x8 bh = *reinterpret_cast<const bf16x8*>(
                    hT + (size_t)(et * 16 + l15) * NN + c0 + ks * 32 + g * 8);
                acc[et] = __builtin_amdgcn_mfma_f32_16x16x32_bf16(pa[ks], bh, acc[et], 0, 0, 0);
            }
        }
    }

    // write partials as fp16 (overwrites this wave's P region -- wave-local)
    #pragma unroll
    for (int et = 0; et < 8; ++et)
        #pragma unroll
        for (int j = 0; j < 4; ++j)
            lds_acc[wv][g * 4 + j][et * 16 + l15] = (_Float16)acc[et][j];
    if (l15 == 0) {
        #pragma unroll
        for (int j = 0; j < 4; ++j) {
            lds_m[wv][g * 4 + j] = m[j];
            lds_l[wv][g * 4 + j] = l[j];
        }
    }
    __syncthreads();

    // combine 8 partials: wave wv owns rows {2wv, 2wv+1}; lane owns 2 cols
    #pragma unroll
    for (int rr = 0; rr < 2; ++rr) {
        const int r = wv * 2 + rr;
        float mp[KVW], M = -__builtin_inff();
        #pragma unroll
        for (int p = 0; p < KVW; ++p) { mp[p] = lds_m[p][r]; M = fmaxf(M, mp[p]); }
        float ep[KVW], L = 0.f;
        #pragma unroll
        for (int p = 0; p < KVW; ++p) { ep[p] = __expf(mp[p] - M); L += lds_l[p][r] * ep[p]; }
        const float invL = 1.f / L;
        #pragma unroll
        for (int cs = 0; cs < 2; ++cs) {
            const int c = lane + cs * 64;
            float s = 0.f;
            #pragma unroll
            for (int p = 0; p < KVW; ++p) s += (float)lds_acc[p][r][c] * ep[p];
            agg[(size_t)(qbase + r) * EE + c] = s * invL;
        }
    }
}

// ---------------------------------------------------------------------------
// Kernel 3: out = relu(agg@wh1+bh1)@wh2 + bh2
// ---------------------------------------------------------------------------
__global__ __launch_bounds__(128) void k_head(
    const float* __restrict__ agg,
    const float* __restrict__ wh1, const float* __restrict__ bh1,
    const float* __restrict__ wh2, const float* __restrict__ bh2,
    float* __restrict__ out)
{
    __shared__ float ag[16][EE + 1];
    __shared__ float h2[16][EE + 1];
    const int t  = threadIdx.x;
    const int rg = t >> 4;
    const int ec = (t & 15) * 8;
    const int ra = rg * 2, rb = ra + 1;
    const int r0b = blockIdx.x * 16;

    #pragma unroll
    for (int r = 0; r < 16; ++r)
        ag[r][t] = agg[(size_t)(r0b + r) * EE + t];
    __syncthreads();
    {
        float a0[8], a1[8];
        #pragma unroll
        for (int j = 0; j < 8; ++j) { float b = bh1[ec + j]; a0[j] = b; a1[j] = b; }
        for (int s = 0; s < EE; ++s) {
            float x0 = ag[ra][s], x1 = ag[rb][s];
            const float* wrow = wh1 + s * EE + ec;
            #pragma unroll
            for (int j = 0; j < 8; ++j) { float w = wrow[j]; a0[j] = fmaf(x0, w, a0[j]); a1[j] = fmaf(x1, w, a1[j]); }
        }
        #pragma unroll
        for (int j = 0; j < 8; ++j) { h2[ra][ec + j] = fmaxf(a0[j], 0.f); h2[rb][ec + j] = fmaxf(a1[j], 0.f); }
    }
    __syncthreads();
    const int r = t >> 3, a = t & 7;
    float o = bh2[a];
    for (int s = 0; s < EE; ++s) o = fmaf(h2[r][s], wh2[s * AA + a], o);
    out[(size_t)(r0b + r) * AA + a] = o;
}

// ---------------------------------------------------------------------------
extern "C" void kernel_launch(void* const* d_in, const int* in_sizes, int n_in,
                              void* d_out, int out_size, void* d_ws, size_t ws_size,
                              hipStream_t stream)
{
    (void)in_sizes; (void)n_in; (void)out_size; (void)ws_size;
    const float* state = (const float*)d_in[0];
    const int*   adj   = (const int*)d_in[1];
    const float* w1  = (const float*)d_in[2];
    const float* b1  = (const float*)d_in[3];
    const float* w2  = (const float*)d_in[4];
    const float* b2  = (const float*)d_in[5];
    const float* wq  = (const float*)d_in[6];
    const float* wk  = (const float*)d_in[7];
    const float* wh1 = (const float*)d_in[8];
    const float* bh1 = (const float*)d_in[9];
    const float* wh2 = (const float*)d_in[10];
    const float* bh2 = (const float*)d_in[11];
    float* out = (float*)d_out;

    char* ws = (char*)d_ws;
    u16*  qb  = (u16*)ws;                                  //  0..2 MB
    u16*  kb  = (u16*)(ws + (size_t)NN * EE * 2);          //  2..4 MB
    u16*  hT  = (u16*)(ws + (size_t)NN * EE * 4);          //  4..6 MB
    float* agg = (float*)(ws + (size_t)NN * EE * 6);       //  6..10 MB
    u64*  msk = (u64*)(ws + (size_t)NN * EE * 6 + (size_t)NN * EE * 4); // 10..18 MB

    k_mlp    <<<NN / 16, 128, 0, stream>>>(state, w1, b1, w2, b2, wq, wk, qb, kb, hT);
    k_adjmask<<<2048, 256, 0, stream>>>(adj, msk);
    k_attn   <<<NN / 16, 512, 0, stream>>>(qb, kb, hT, msk, agg);
    k_head   <<<NN / 16, 128, 0, stream>>>(agg, wh1, bh1, wh2, bh2, out);
}

// Round 13
// 301.926 us; speedup vs baseline: 1.9460x; 1.1676x over previous
//
#include <hip/hip_runtime.h>
#include <hip/hip_bf16.h>
#include <cstdint>

#define NN 8192
#define EE 128
#define AA 8
#define QSCALE 0.08838834764831845f   // 1/sqrt(128)
#define NKVS 8                         // KV splits (blocks per q-tile)
#define KVLEN (NN / NKVS)              // 1024 cols per block
#define NIT (KVLEN / 64)               // 16 chunks per block
#define NW (NN / 64)                   // 128 mask words per row

typedef __attribute__((ext_vector_type(8))) short bf16x8;
typedef __attribute__((ext_vector_type(4))) float f32x4;
typedef unsigned short u16;
typedef unsigned int u32;
typedef unsigned long long u64;

__device__ __forceinline__ u16 bf16_bits(float x) {
    union { float f; u32 u; } v; v.f = x;
    u32 r = v.u + 0x7fffu + ((v.u >> 16) & 1u);   // RNE
    return (u16)(r >> 16);
}

// ---------------------------------------------------------------------------
// Kernel 0: pack adj (int32 {0,1}, 256MB) into a bitmask (8MB).
// ---------------------------------------------------------------------------
__global__ __launch_bounds__(256) void k_adjmask(
    const int* __restrict__ adj, u64* __restrict__ msk)
{
    const u32 gwave  = (blockIdx.x * 256 + threadIdx.x) >> 6;
    const u32 nwaves = (gridDim.x * 256) >> 6;
    const int lane   = threadIdx.x & 63;
    const size_t nwords = (size_t)NN * NW;   // 1,048,576
    for (size_t w = (size_t)gwave * 4; w < nwords; w += (size_t)nwaves * 4) {
        u64 b[4];
        #pragma unroll
        for (int u = 0; u < 4; ++u)
            b[u] = __ballot(adj[(w + u) * 64 + lane] != 0);
        if (lane == 0) {
            *reinterpret_cast<ulonglong2*>(&msk[w])     = ulonglong2{b[0], b[1]};
            *reinterpret_cast<ulonglong2*>(&msk[w + 2]) = ulonglong2{b[2], b[3]};
        }
    }
}

// ---------------------------------------------------------------------------
// Kernel 1: h = relu(state@w1+b1)@w2+b2 ; q = (h@wq)/sqrt(E) ; k = h@wk
// Writes q,k as bf16 [N][E] and hT as bf16 [E][N].
// ---------------------------------------------------------------------------
__global__ __launch_bounds__(128) void k_mlp(
    const float* __restrict__ state,
    const float* __restrict__ w1, const float* __restrict__ b1,
    const float* __restrict__ w2, const float* __restrict__ b2,
    const float* __restrict__ wq, const float* __restrict__ wk,
    u16* __restrict__ qb, u16* __restrict__ kb, u16* __restrict__ hT)
{
    __shared__ float st[16][EE + 1];   // state tile, then reused for h
    __shared__ float h1[16][EE + 1];
    const int t  = threadIdx.x;
    const int rg = t >> 4;            // 0..7
    const int ec = (t & 15) * 8;      // col base
    const int ra = rg * 2, rb = ra + 1;
    const int r0b = blockIdx.x * 16;

    #pragma unroll
    for (int r = 0; r < 16; ++r)
        st[r][t] = state[(size_t)(r0b + r) * EE + t];
    __syncthreads();

    // stage 1: h1 = relu(st@w1 + b1)
    {
        float a0[8], a1[8];
        #pragma unroll
        for (int j = 0; j < 8; ++j) { float b = b1[ec + j]; a0[j] = b; a1[j] = b; }
        for (int s = 0; s < EE; ++s) {
            float x0 = st[ra][s], x1 = st[rb][s];
            const float* wrow = w1 + s * EE + ec;
            #pragma unroll
            for (int j = 0; j < 8; ++j) { float w = wrow[j]; a0[j] = fmaf(x0, w, a0[j]); a1[j] = fmaf(x1, w, a1[j]); }
        }
        __syncthreads();
        #pragma unroll
        for (int j = 0; j < 8; ++j) { h1[ra][ec + j] = fmaxf(a0[j], 0.f); h1[rb][ec + j] = fmaxf(a1[j], 0.f); }
    }
    __syncthreads();

    // stage 2: h = h1@w2 + b2
    float hva[8], hvb[8];
    {
        float a0[8], a1[8];
        #pragma unroll
        for (int j = 0; j < 8; ++j) { float b = b2[ec + j]; a0[j] = b; a1[j] = b; }
        for (int s = 0; s < EE; ++s) {
            float x0 = h1[ra][s], x1 = h1[rb][s];
            const float* wrow = w2 + s * EE + ec;
            #pragma unroll
            for (int j = 0; j < 8; ++j) { float w = wrow[j]; a0[j] = fmaf(x0, w, a0[j]); a1[j] = fmaf(x1, w, a1[j]); }
        }
        #pragma unroll
        for (int j = 0; j < 8; ++j) {
            st[ra][ec + j] = a0[j]; st[rb][ec + j] = a1[j];
            hva[j] = a0[j]; hvb[j] = a1[j];
        }
    }
    __syncthreads();

    // stage 3: q = (h@wq)*QSCALE, k = h@wk
    {
        float q0[8], q1[8], k0[8], k1[8];
        #pragma unroll
        for (int j = 0; j < 8; ++j) { q0[j] = 0.f; q1[j] = 0.f; k0[j] = 0.f; k1[j] = 0.f; }
        for (int s = 0; s < EE; ++s) {
            float x0 = st[ra][s], x1 = st[rb][s];
            const float* wqr = wq + s * EE + ec;
            const float* wkr = wk + s * EE + ec;
            #pragma unroll
            for (int j = 0; j < 8; ++j) {
                float a = wqr[j], b = wkr[j];
                q0[j] = fmaf(x0, a, q0[j]); q1[j] = fmaf(x1, a, q1[j]);
                k0[j] = fmaf(x0, b, k0[j]); k1[j] = fmaf(x1, b, k1[j]);
            }
        }
        bf16x8 vq0, vq1, vk0, vk1;
        #pragma unroll
        for (int j = 0; j < 8; ++j) {
            vq0[j] = (short)bf16_bits(q0[j] * QSCALE);
            vq1[j] = (short)bf16_bits(q1[j] * QSCALE);
            vk0[j] = (short)bf16_bits(k0[j]);
            vk1[j] = (short)bf16_bits(k1[j]);
        }
        *reinterpret_cast<bf16x8*>(qb + (size_t)(r0b + ra) * EE + ec) = vq0;
        *reinterpret_cast<bf16x8*>(qb + (size_t)(r0b + rb) * EE + ec) = vq1;
        *reinterpret_cast<bf16x8*>(kb + (size_t)(r0b + ra) * EE + ec) = vk0;
        *reinterpret_cast<bf16x8*>(kb + (size_t)(r0b + rb) * EE + ec) = vk1;
    }

    #pragma unroll
    for (int j = 0; j < 8; ++j) {
        u32 pack = (u32)bf16_bits(hva[j]) | ((u32)bf16_bits(hvb[j]) << 16);
        *reinterpret_cast<u32*>(hT + (size_t)(ec + j) * NN + r0b + ra) = pack;
    }
}

// ---------------------------------------------------------------------------
// Kernel 2: flash attention, restructured for block-level KV SHARING.
// Block = 8 waves x 16 q-rows = 128 q-rows; all waves process the SAME
// 64-col KV chunk, staged once per chunk in LDS (double-buffered, XOR
// swizzle, issue-early/write-late). 8x fewer L1 line-requests than the
// per-wave-KV-split design (R12's measured bottleneck).
// Grid = 64 q-tiles x 8 KV-splits; flash partials (m,l,fp16 acc) -> global.
// ---------------------------------------------------------------------------
__global__ __launch_bounds__(512, 4) void k_attn(
    const u16* __restrict__ qb, const u16* __restrict__ kb,
    const u16* __restrict__ hT, const u64* __restrict__ msk,
    _Float16* __restrict__ pacc, float* __restrict__ pm, float* __restrict__ pl)
{
    // LDS: K dbuf 2x16KB | hT dbuf 2x16KB | P tiles 8x2KB  = 80 KB
    __shared__ char smem[81920];

    const int tid  = threadIdx.x;
    const int wv   = tid >> 6;
    const int lane = tid & 63;
    const int l15  = lane & 15;
    const int g    = lane >> 4;
    const int qt   = blockIdx.x >> 3;
    const int kvs  = blockIdx.x & 7;
    const int qr0  = qt * 128 + wv * 16;
    const int kv0  = kvs * KVLEN;

    // Q fragments in registers for the whole kernel
    bf16x8 qf[4];
    #pragma unroll
    for (int ks = 0; ks < 4; ++ks)
        qf[ks] = *reinterpret_cast<const bf16x8*>(qb + (size_t)(qr0 + l15) * EE + ks * 32 + g * 8);

    f32x4 acc[8];
    #pragma unroll
    for (int et = 0; et < 8; ++et) acc[et] = f32x4{0.f, 0.f, 0.f, 0.f};
    float m[4], l[4];
    #pragma unroll
    for (int j = 0; j < 4; ++j) { m[j] = -__builtin_inff(); l[j] = 0.f; }

    const u64* mbase = msk + (size_t)(qr0 + g * 4) * NW + kvs * NIT;
    u16* plw = reinterpret_cast<u16*>(smem + 65536 + wv * 2048);   // [16][64]

    // staging geometry: 512 threads cover K(64x256B) and hT(128x128B), 32B each
    const int krow = tid >> 3, kseg = (tid & 7) * 32;
    const int he   = tid >> 2, hseg = (tid & 3) * 32;
    const int ksw  = (krow & 7) << 4;
    const int hsw  = (he & 7) << 4;
    bf16x8 kr0, kr1, hr0, hr1;

    auto LOADG = [&](int c0) {   // issue global loads (latency hides under compute)
        kr0 = *reinterpret_cast<const bf16x8*>(kb + (size_t)(c0 + krow) * EE + kseg / 2);
        kr1 = *reinterpret_cast<const bf16x8*>(kb + (size_t)(c0 + krow) * EE + kseg / 2 + 8);
        hr0 = *reinterpret_cast<const bf16x8*>(hT + (size_t)he * NN + c0 + hseg / 2);
        hr1 = *reinterpret_cast<const bf16x8*>(hT + (size_t)he * NN + c0 + hseg / 2 + 8);
    };
    auto WLDS = [&](int b) {     // swizzled LDS writes (XOR byte ^= (row&7)<<4)
        char* kB = smem + b * 16384;
        *reinterpret_cast<bf16x8*>(kB + krow * 256 + (kseg ^ ksw)) = kr0;
        *reinterpret_cast<bf16x8*>(kB + krow * 256 + ((kseg + 16) ^ ksw)) = kr1;
        char* hB = smem + 32768 + b * 16384;
        *reinterpret_cast<bf16x8*>(hB + he * 128 + (hseg ^ hsw)) = hr0;
        *reinterpret_cast<bf16x8*>(hB + he * 128 + ((hseg + 16) ^ hsw)) = hr1;
    };

    LOADG(kv0);
    WLDS(0);
    __syncthreads();

    const int rsw = (l15 & 7) << 4;   // read-side swizzle (row&7 == l15&7)

    for (int cc = 0; cc < NIT; ++cc) {
        if (cc + 1 < NIT) LOADG(kv0 + (cc + 1) * 64);   // prefetch next chunk
        const char* kB = smem + (cc & 1) * 16384;
        const char* hB = smem + 32768 + (cc & 1) * 16384;

        u64 mw[4];
        #pragma unroll
        for (int j = 0; j < 4; ++j)
            mw[j] = mbase[(size_t)j * NW + cc];

        // S = q @ k^T from staged K
        f32x4 sv[4];
        #pragma unroll
        for (int nt = 0; nt < 4; ++nt) sv[nt] = f32x4{0.f, 0.f, 0.f, 0.f};
        #pragma unroll
        for (int nt = 0; nt < 4; ++nt) {
            #pragma unroll
            for (int ks = 0; ks < 4; ++ks) {
                bf16x8 bk = *reinterpret_cast<const bf16x8*>(
                    kB + (nt * 16 + l15) * 256 + ((ks * 64 + g * 16) ^ rsw));
                sv[nt] = __builtin_amdgcn_mfma_f32_16x16x32_bf16(qf[ks], bk, sv[nt], 0, 0, 0);
            }
        }
        // adjacency mask via bit test
        float ms[4][4];
        #pragma unroll
        for (int nt = 0; nt < 4; ++nt)
            #pragma unroll
            for (int j = 0; j < 4; ++j)
                ms[nt][j] = ((mw[j] >> (nt * 16 + l15)) & 1ull) ? sv[nt][j]
                                                                : -__builtin_inff();

        // online softmax
        float alpha[4], mn[4];
        #pragma unroll
        for (int j = 0; j < 4; ++j) {
            float rm = fmaxf(fmaxf(ms[0][j], ms[1][j]), fmaxf(ms[2][j], ms[3][j]));
            rm = fmaxf(rm, __shfl_xor(rm, 1));
            rm = fmaxf(rm, __shfl_xor(rm, 2));
            rm = fmaxf(rm, __shfl_xor(rm, 4));
            rm = fmaxf(rm, __shfl_xor(rm, 8));
            mn[j] = fmaxf(m[j], rm);
            alpha[j] = (mn[j] == m[j]) ? 1.f : __expf(m[j] - mn[j]);
            m[j] = mn[j];
        }
        float rs[4] = {0.f, 0.f, 0.f, 0.f};
        u16 pb[4][4];
        #pragma unroll
        for (int nt = 0; nt < 4; ++nt) {
            #pragma unroll
            for (int j = 0; j < 4; ++j) {
                float pv = (mn[j] == -__builtin_inff()) ? 0.f : __expf(ms[nt][j] - mn[j]);
                rs[j] += pv;
                pb[nt][j] = bf16_bits(pv);
            }
        }
        #pragma unroll
        for (int j = 0; j < 4; ++j) {
            float r = rs[j];
            r += __shfl_xor(r, 1);
            r += __shfl_xor(r, 2);
            r += __shfl_xor(r, 4);
            r += __shfl_xor(r, 8);
            l[j] = l[j] * alpha[j] + r;
        }
        // P (D-layout) -> per-wave LDS tile -> A-frag (XOR swizzle)
        #pragma unroll
        for (int nt = 0; nt < 4; ++nt) {
            #pragma unroll
            for (int j = 0; j < 4; ++j) {
                int row = g * 4 + j;
                int col = nt * 16 + l15;
                plw[row * 64 + (col ^ ((row & 7) << 3))] = pb[nt][j];
            }
        }
        asm volatile("s_waitcnt lgkmcnt(0)" ::: "memory");
        __builtin_amdgcn_sched_barrier(0);
        bf16x8 pa[2];
        #pragma unroll
        for (int ks = 0; ks < 2; ++ks) {
            int eo = (ks * 32 + g * 8) ^ ((l15 & 7) << 3);
            pa[ks] = *reinterpret_cast<const bf16x8*>(&plw[l15 * 64 + eo]);
        }
        // rescale + PV from staged hT
        f32x4 avv = {alpha[0], alpha[1], alpha[2], alpha[3]};
        #pragma unroll
        for (int et = 0; et < 8; ++et) {
            acc[et] = acc[et] * avv;
            #pragma unroll
            for (int ks = 0; ks < 2; ++ks) {
                bf16x8 bh = *reinterpret_cast<const bf16x8*>(
                    hB + (et * 16 + l15) * 128 + ((ks * 64 + g * 16) ^ rsw));
                acc[et] = __builtin_amdgcn_mfma_f32_16x16x32_bf16(pa[ks], bh, acc[et], 0, 0, 0);
            }
        }
        if (cc + 1 < NIT) WLDS((cc + 1) & 1);   // write-late into idle buffer
        __syncthreads();
    }

    // write flash partials to global (wave-local rows, no block combine)
    const size_t pbase = (size_t)kvs * NN + qr0;
    #pragma unroll
    for (int et = 0; et < 8; ++et)
        #pragma unroll
        for (int j = 0; j < 4; ++j)
            pacc[(pbase + g * 4 + j) * EE + et * 16 + l15] = (_Float16)acc[et][j];
    if (l15 == 0) {
        #pragma unroll
        for (int j = 0; j < 4; ++j) {
            pm[pbase + g * 4 + j] = m[j];
            pl[pbase + g * 4 + j] = l[j];
        }
    }
}

// ---------------------------------------------------------------------------
// Kernel 2b: combine the 8 KV-split partials per q-row.
// ---------------------------------------------------------------------------
__global__ __launch_bounds__(256) void k_comb(
    const _Float16* __restrict__ pacc, const float* __restrict__ pm,
    const float* __restrict__ pl, float* __restrict__ agg)
{
    const int row = blockIdx.x * 2 + (threadIdx.x >> 7);
    const int col = threadIdx.x & 127;
    float mp[NKVS], M = -__builtin_inff();
    #pragma unroll
    for (int p = 0; p < NKVS; ++p) { mp[p] = pm[(size_t)p * NN + row]; M = fmaxf(M, mp[p]); }
    float ep[NKVS], L = 0.f;
    #pragma unroll
    for (int p = 0; p < NKVS; ++p) { ep[p] = __expf(mp[p] - M); L += pl[(size_t)p * NN + row] * ep[p]; }
    float s = 0.f;
    #pragma unroll
    for (int p = 0; p < NKVS; ++p)
        s += (float)pacc[((size_t)p * NN + row) * EE + col] * ep[p];
    agg[(size_t)row * EE + col] = s / L;
}

// ---------------------------------------------------------------------------
// Kernel 3: out = relu(agg@wh1+bh1)@wh2 + bh2
// ---------------------------------------------------------------------------
__global__ __launch_bounds__(128) void k_head(
    const float* __restrict__ agg,
    const float* __restrict__ wh1, const float* __restrict__ bh1,
    const float* __restrict__ wh2, const float* __restrict__ bh2,
    float* __restrict__ out)
{
    __shared__ float ag[16][EE + 1];
    __shared__ float h2[16][EE + 1];
    const int t  = threadIdx.x;
    const int rg = t >> 4;
    const int ec = (t & 15) * 8;
    const int ra = rg * 2, rb = ra + 1;
    const int r0b = blockIdx.x * 16;

    #pragma unroll
    for (int r = 0; r < 16; ++r)
        ag[r][t] = agg[(size_t)(r0b + r) * EE + t];
    __syncthreads();
    {
        float a0[8], a1[8];
        #pragma unroll
        for (int j = 0; j < 8; ++j) { float b = bh1[ec + j]; a0[j] = b; a1[j] = b; }
        for (int s = 0; s < EE; ++s) {
            float x0 = ag[ra][s], x1 = ag[rb][s];
            const float* wrow = wh1 + s * EE + ec;
            #pragma unroll
            for (int j = 0; j < 8; ++j) { float w = wrow[j]; a0[j] = fmaf(x0, w, a0[j]); a1[j] = fmaf(x1, w, a1[j]); }
        }
        #pragma unroll
        for (int j = 0; j < 8; ++j) { h2[ra][ec + j] = fmaxf(a0[j], 0.f); h2[rb][ec + j] = fmaxf(a1[j], 0.f); }
    }
    __syncthreads();
    const int r = t >> 3, a = t & 7;
    float o = bh2[a];
    for (int s = 0; s < EE; ++s) o = fmaf(h2[r][s], wh2[s * AA + a], o);
    out[(size_t)(r0b + r) * AA + a] = o;
}

// ---------------------------------------------------------------------------
extern "C" void kernel_launch(void* const* d_in, const int* in_sizes, int n_in,
                              void* d_out, int out_size, void* d_ws, size_t ws_size,
                              hipStream_t stream)
{
    (void)in_sizes; (void)n_in; (void)out_size; (void)ws_size;
    const float* state = (const float*)d_in[0];
    const int*   adj   = (const int*)d_in[1];
    const float* w1  = (const float*)d_in[2];
    const float* b1  = (const float*)d_in[3];
    const float* w2  = (const float*)d_in[4];
    const float* b2  = (const float*)d_in[5];
    const float* wq  = (const float*)d_in[6];
    const float* wk  = (const float*)d_in[7];
    const float* wh1 = (const float*)d_in[8];
    const float* bh1 = (const float*)d_in[9];
    const float* wh2 = (const float*)d_in[10];
    const float* bh2 = (const float*)d_in[11];
    float* out = (float*)d_out;

    char* ws = (char*)d_ws;
    const size_t MB = 1024 * 1024;
    u16*      qb   = (u16*)ws;                       //  0..2 MB
    u16*      kb   = (u16*)(ws + 2 * MB);            //  2..4 MB
    u16*      hT   = (u16*)(ws + 4 * MB);            //  4..6 MB
    float*    agg  = (float*)(ws + 6 * MB);          //  6..10 MB
    u64*      msk  = (u64*)(ws + 10 * MB);           // 10..18 MB
    _Float16* pacc = (_Float16*)(ws + 18 * MB);      // 18..34 MB (8*8192*128 fp16)
    float*    pm   = (float*)(ws + 34 * MB);         // 34..34.25 MB
    float*    pl   = (float*)(ws + 34 * MB + 256 * 1024); // 34.25..34.5 MB

    k_mlp    <<<NN / 16, 128, 0, stream>>>(state, w1, b1, w2, b2, wq, wk, qb, kb, hT);
    k_adjmask<<<2048, 256, 0, stream>>>(adj, msk);
    k_attn   <<<(NN / 128) * NKVS, 512, 0, stream>>>(qb, kb, hT, msk, pacc, pm, pl);
    k_comb   <<<NN / 2, 256, 0, stream>>>(pacc, pm, pl, agg);
    k_head   <<<NN / 16, 128, 0, stream>>>(agg, wh1, bh1, wh2, bh2, out);
}

// Round 14
// 197.195 us; speedup vs baseline: 2.9795x; 1.5311x over previous
//
#include <hip/hip_runtime.h>
#include <hip/hip_bf16.h>
#include <cstdint>

#define NN 8192
#define EE 128
#define AA 8
#define QSCALE 0.08838834764831845f   // 1/sqrt(128)
#define NKVS 8                         // KV splits
#define KVLEN (NN / NKVS)              // 1024 cols per block
#define NIT (KVLEN / 64)               // 16 chunks per block
#define NW (NN / 64)                   // 128 mask words per row

typedef __attribute__((ext_vector_type(8))) short bf16x8;
typedef __attribute__((ext_vector_type(16))) float f32x16;
typedef unsigned short u16;
typedef unsigned int u32;
typedef unsigned long long u64;

__device__ __forceinline__ u16 bf16_bits(float x) {
    union { float f; u32 u; } v; v.f = x;
    u32 r = v.u + 0x7fffu + ((v.u >> 16) & 1u);   // RNE
    return (u16)(r >> 16);
}

__device__ __forceinline__ u32 cvtpk_bf16(float lo, float hi) {
    u32 r;
    asm("v_cvt_pk_bf16_f32 %0, %1, %2" : "=v"(r) : "v"(lo), "v"(hi));
    return r;
}

// ---------------------------------------------------------------------------
// Kernel 0: pack adj (int32 {0,1}, 256MB) into a bitmask (8MB).
// ---------------------------------------------------------------------------
__global__ __launch_bounds__(256) void k_adjmask(
    const int* __restrict__ adj, u64* __restrict__ msk)
{
    const u32 gwave  = (blockIdx.x * 256 + threadIdx.x) >> 6;
    const u32 nwaves = (gridDim.x * 256) >> 6;
    const int lane   = threadIdx.x & 63;
    const size_t nwords = (size_t)NN * NW;   // 1,048,576
    for (size_t w = (size_t)gwave * 4; w < nwords; w += (size_t)nwaves * 4) {
        u64 b[4];
        #pragma unroll
        for (int u = 0; u < 4; ++u)
            b[u] = __ballot(adj[(w + u) * 64 + lane] != 0);
        if (lane == 0) {
            *reinterpret_cast<ulonglong2*>(&msk[w])     = ulonglong2{b[0], b[1]};
            *reinterpret_cast<ulonglong2*>(&msk[w + 2]) = ulonglong2{b[2], b[3]};
        }
    }
}

// ---------------------------------------------------------------------------
// Kernel 1: h = relu(state@w1+b1)@w2+b2 ; q = (h@wq)/sqrt(E) ; k = h@wk
// Writes q,k as bf16 [N][E] and hT as bf16 [E][N].
// ---------------------------------------------------------------------------
__global__ __launch_bounds__(128) void k_mlp(
    const float* __restrict__ state,
    const float* __restrict__ w1, const float* __restrict__ b1,
    const float* __restrict__ w2, const float* __restrict__ b2,
    const float* __restrict__ wq, const float* __restrict__ wk,
    u16* __restrict__ qb, u16* __restrict__ kb, u16* __restrict__ hT)
{
    __shared__ float st[16][EE + 1];
    __shared__ float h1[16][EE + 1];
    const int t  = threadIdx.x;
    const int rg = t >> 4;
    const int ec = (t & 15) * 8;
    const int ra = rg * 2, rb = ra + 1;
    const int r0b = blockIdx.x * 16;

    #pragma unroll
    for (int r = 0; r < 16; ++r)
        st[r][t] = state[(size_t)(r0b + r) * EE + t];
    __syncthreads();

    {
        float a0[8], a1[8];
        #pragma unroll
        for (int j = 0; j < 8; ++j) { float b = b1[ec + j]; a0[j] = b; a1[j] = b; }
        for (int s = 0; s < EE; ++s) {
            float x0 = st[ra][s], x1 = st[rb][s];
            const float* wrow = w1 + s * EE + ec;
            #pragma unroll
            for (int j = 0; j < 8; ++j) { float w = wrow[j]; a0[j] = fmaf(x0, w, a0[j]); a1[j] = fmaf(x1, w, a1[j]); }
        }
        __syncthreads();
        #pragma unroll
        for (int j = 0; j < 8; ++j) { h1[ra][ec + j] = fmaxf(a0[j], 0.f); h1[rb][ec + j] = fmaxf(a1[j], 0.f); }
    }
    __syncthreads();

    float hva[8], hvb[8];
    {
        float a0[8], a1[8];
        #pragma unroll
        for (int j = 0; j < 8; ++j) { float b = b2[ec + j]; a0[j] = b; a1[j] = b; }
        for (int s = 0; s < EE; ++s) {
            float x0 = h1[ra][s], x1 = h1[rb][s];
            const float* wrow = w2 + s * EE + ec;
            #pragma unroll
            for (int j = 0; j < 8; ++j) { float w = wrow[j]; a0[j] = fmaf(x0, w, a0[j]); a1[j] = fmaf(x1, w, a1[j]); }
        }
        #pragma unroll
        for (int j = 0; j < 8; ++j) {
            st[ra][ec + j] = a0[j]; st[rb][ec + j] = a1[j];
            hva[j] = a0[j]; hvb[j] = a1[j];
        }
    }
    __syncthreads();

    {
        float q0[8], q1[8], k0[8], k1[8];
        #pragma unroll
        for (int j = 0; j < 8; ++j) { q0[j] = 0.f; q1[j] = 0.f; k0[j] = 0.f; k1[j] = 0.f; }
        for (int s = 0; s < EE; ++s) {
            float x0 = st[ra][s], x1 = st[rb][s];
            const float* wqr = wq + s * EE + ec;
            const float* wkr = wk + s * EE + ec;
            #pragma unroll
            for (int j = 0; j < 8; ++j) {
                float a = wqr[j], b = wkr[j];
                q0[j] = fmaf(x0, a, q0[j]); q1[j] = fmaf(x1, a, q1[j]);
                k0[j] = fmaf(x0, b, k0[j]); k1[j] = fmaf(x1, b, k1[j]);
            }
        }
        bf16x8 vq0, vq1, vk0, vk1;
        #pragma unroll
        for (int j = 0; j < 8; ++j) {
            vq0[j] = (short)bf16_bits(q0[j] * QSCALE);
            vq1[j] = (short)bf16_bits(q1[j] * QSCALE);
            vk0[j] = (short)bf16_bits(k0[j]);
            vk1[j] = (short)bf16_bits(k1[j]);
        }
        *reinterpret_cast<bf16x8*>(qb + (size_t)(r0b + ra) * EE + ec) = vq0;
        *reinterpret_cast<bf16x8*>(qb + (size_t)(r0b + rb) * EE + ec) = vq1;
        *reinterpret_cast<bf16x8*>(kb + (size_t)(r0b + ra) * EE + ec) = vk0;
        *reinterpret_cast<bf16x8*>(kb + (size_t)(r0b + rb) * EE + ec) = vk1;
    }

    #pragma unroll
    for (int j = 0; j < 8; ++j) {
        u32 pack = (u32)bf16_bits(hva[j]) | ((u32)bf16_bits(hvb[j]) << 16);
        *reinterpret_cast<u32*>(hT + (size_t)(ec + j) * NN + r0b + ra) = pack;
    }
}

// ---------------------------------------------------------------------------
// Kernel 2: flash attention, 32x32 MFMA with SWAPPED QK^T (m214/T12 style).
// Block = 4 waves x 32 q-rows = 128 q-rows, shared KV chunk staged in LDS
// (double-buffered, XOR swizzle, issue-early/write-late).
// sv = mfma(K,Q) -> lane holds S^T[k][q=lane&31]: softmax lane-local
// (1 shfl_xor(32) per reduce); P reaches PV B-frag via cvt_pk + 8
// shfl_xor(32) -- NO P-LDS round trip, no mid-chunk waitcnt drains.
// PV computes agg^T[e][q] = mfma(hT_frag, P^T_frag); alpha lane-local.
// ---------------------------------------------------------------------------
__global__ __launch_bounds__(256) void k_attn(
    const u16* __restrict__ qb, const u16* __restrict__ kb,
    const u16* __restrict__ hT, const u64* __restrict__ msk,
    _Float16* __restrict__ pacc, float* __restrict__ pm, float* __restrict__ pl)
{
    __shared__ char smem[65536];   // K dbuf 2x16KB @0 | hT dbuf 2x16KB @32768

    const int tid  = threadIdx.x;
    const int wv   = tid >> 6;
    const int lane = tid & 63;
    const int l31  = lane & 31;
    const int hf   = lane >> 5;          // half: 0 or 1
    const int qt   = blockIdx.x >> 3;
    const int kvs  = blockIdx.x & 7;
    const int qr0  = qt * 128 + wv * 32;
    const int kv0  = kvs * KVLEN;

    // Q fragments (B-operand of swapped QK): lane holds Q[qr0+l31][16s+8hf+i]
    bf16x8 qf[8];
    #pragma unroll
    for (int s = 0; s < 8; ++s)
        qf[s] = *reinterpret_cast<const bf16x8*>(
            qb + (size_t)(qr0 + l31) * EE + s * 16 + hf * 8);

    f32x16 acc[4];
    #pragma unroll
    for (int et = 0; et < 4; ++et)
        #pragma unroll
        for (int r = 0; r < 16; ++r) acc[et][r] = 0.f;
    float m = -__builtin_inff(), lsum = 0.f;

    const u64* mrow = msk + (size_t)(qr0 + l31) * NW + kvs * NIT;

    // staging: 256 threads, 64B K + 64B hT each
    const int kr = tid >> 2, kc = (tid & 3) * 32;   // K row, elem base
    const int hr = tid >> 1, hc = (tid & 1) * 32;   // hT row, elem base
    const int ksw = (kr & 7) << 4, hsw = (hr & 7) << 4;
    bf16x8 kg[4], hg[4];

    auto LOADG = [&](int c0) {
        #pragma unroll
        for (int u = 0; u < 4; ++u)
            kg[u] = *reinterpret_cast<const bf16x8*>(kb + (size_t)(c0 + kr) * EE + kc + 8 * u);
        #pragma unroll
        for (int u = 0; u < 4; ++u)
            hg[u] = *reinterpret_cast<const bf16x8*>(hT + (size_t)hr * NN + c0 + hc + 8 * u);
    };
    auto WLDS = [&](int b) {
        char* kB = smem + b * 16384;
        #pragma unroll
        for (int u = 0; u < 4; ++u)
            *reinterpret_cast<bf16x8*>(kB + kr * 256 + ((kc * 2 + 16 * u) ^ ksw)) = kg[u];
        char* hB = smem + 32768 + b * 16384;
        #pragma unroll
        for (int u = 0; u < 4; ++u)
            *reinterpret_cast<bf16x8*>(hB + hr * 128 + ((hc * 2 + 16 * u) ^ hsw)) = hg[u];
    };

    LOADG(kv0);
    WLDS(0);
    __syncthreads();

    const int rsw = (l31 & 7) << 4;   // read-side swizzle

    for (int cc = 0; cc < NIT; ++cc) {
        if (cc + 1 < NIT) LOADG(kv0 + (cc + 1) * 64);
        const char* kB = smem + (cc & 1) * 16384;
        const char* hB = smem + 32768 + (cc & 1) * 16384;
        const u64 mw = mrow[cc];

        // S^T = K @ Q^T: two 32x32 tiles (k-rows 0-31, 32-63), K-dim = 128
        f32x16 sv0, sv1;
        #pragma unroll
        for (int r = 0; r < 16; ++r) { sv0[r] = 0.f; sv1[r] = 0.f; }
        #pragma unroll
        for (int s = 0; s < 8; ++s) {
            bf16x8 a0 = *reinterpret_cast<const bf16x8*>(
                kB + l31 * 256 + ((s * 32 + hf * 16) ^ rsw));
            sv0 = __builtin_amdgcn_mfma_f32_32x32x16_bf16(a0, qf[s], sv0, 0, 0, 0);
            bf16x8 a1 = *reinterpret_cast<const bf16x8*>(
                kB + (32 + l31) * 256 + ((s * 32 + hf * 16) ^ rsw));
            sv1 = __builtin_amdgcn_mfma_f32_32x32x16_bf16(a1, qf[s], sv1, 0, 0, 0);
        }

        // mask + row max (lane-local: q = l31; k = 32t + (r&3)+8*(r>>2)+4hf)
        float pv[32];
        float rm = -__builtin_inff();
        #pragma unroll
        for (int r = 0; r < 16; ++r) {
            int k0i = (r & 3) + 8 * (r >> 2) + 4 * hf;
            float v0 = ((mw >> k0i) & 1ull) ? sv0[r] : -__builtin_inff();
            float v1 = ((mw >> (k0i + 32)) & 1ull) ? sv1[r] : -__builtin_inff();
            pv[r] = v0; pv[16 + r] = v1;
            rm = fmaxf(rm, fmaxf(v0, v1));
        }
        rm = fmaxf(rm, __shfl_xor(rm, 32));
        const float mn2 = fmaxf(m, rm);
        const float alpha = (mn2 == m) ? 1.f : __expf(m - mn2);
        m = mn2;

        float rs = 0.f;
        const bool dead = (mn2 == -__builtin_inff());
        #pragma unroll
        for (int i = 0; i < 32; ++i) {
            float p = dead ? 0.f : __expf(pv[i] - mn2);
            pv[i] = p;
            rs += p;
        }
        rs += __shfl_xor(rs, 32);
        lsum = lsum * alpha + rs;

        // pack P into 8 quads (2 u32 words each), k-ascending
        u32 w[8][2];
        #pragma unroll
        for (int qd = 0; qd < 8; ++qd) {
            int base = 16 * (qd >> 2) + 4 * (qd & 3);
            w[qd][0] = cvtpk_bf16(pv[base], pv[base + 1]);
            w[qd][1] = cvtpk_bf16(pv[base + 2], pv[base + 3]);
        }

        // rescale acc, then PV: agg^T[e][q] += hT_frag @ P^T_frag
        #pragma unroll
        for (int et = 0; et < 4; ++et)
            #pragma unroll
            for (int r = 0; r < 16; ++r) acc[et][r] *= alpha;

        #pragma unroll
        for (int s = 0; s < 4; ++s) {
            u32 s0 = hf == 0 ? w[2 * s + 1][0] : w[2 * s][0];
            u32 s1 = hf == 0 ? w[2 * s + 1][1] : w[2 * s][1];
            u32 r0 = __shfl_xor(s0, 32);
            u32 r1 = __shfl_xor(s1, 32);
            union { u32 u[4]; bf16x8 v; } b2;
            b2.u[0] = hf == 0 ? w[2 * s][0] : r0;
            b2.u[1] = hf == 0 ? w[2 * s][1] : r1;
            b2.u[2] = hf == 0 ? r0 : w[2 * s + 1][0];
            b2.u[3] = hf == 0 ? r1 : w[2 * s + 1][1];
            #pragma unroll
            for (int et = 0; et < 4; ++et) {
                bf16x8 a2 = *reinterpret_cast<const bf16x8*>(
                    hB + (32 * et + l31) * 128 + ((s * 32 + hf * 16) ^ rsw));
                acc[et] = __builtin_amdgcn_mfma_f32_32x32x16_bf16(a2, b2.v, acc[et], 0, 0, 0);
            }
        }
        if (cc + 1 < NIT) WLDS((cc + 1) & 1);
        __syncthreads();
    }

    // epilogue: store agg^T partials (lane: q = l31, e = 32et+(r&3)+8(r>>2)+4hf)
    const size_t pbase = (size_t)kvs * NN + qr0;
    #pragma unroll
    for (int et = 0; et < 4; ++et)
        #pragma unroll
        for (int r = 0; r < 16; ++r) {
            int e = 32 * et + (r & 3) + 8 * (r >> 2) + 4 * hf;
            pacc[(pbase + l31) * EE + e] = (_Float16)acc[et][r];
        }
    if (hf == 0) {
        pm[pbase + l31] = m;
        pl[pbase + l31] = lsum;
    }
}

// ---------------------------------------------------------------------------
// Kernel 2b: combine the 8 KV-split partials per q-row.
// ---------------------------------------------------------------------------
__global__ __launch_bounds__(256) void k_comb(
    const _Float16* __restrict__ pacc, const float* __restrict__ pm,
    const float* __restrict__ pl, float* __restrict__ agg)
{
    const int row = blockIdx.x * 2 + (threadIdx.x >> 7);
    const int col = threadIdx.x & 127;
    float mp[NKVS], M = -__builtin_inff();
    #pragma unroll
    for (int p = 0; p < NKVS; ++p) { mp[p] = pm[(size_t)p * NN + row]; M = fmaxf(M, mp[p]); }
    float ep[NKVS], L = 0.f;
    #pragma unroll
    for (int p = 0; p < NKVS; ++p) { ep[p] = __expf(mp[p] - M); L += pl[(size_t)p * NN + row] * ep[p]; }
    float s = 0.f;
    #pragma unroll
    for (int p = 0; p < NKVS; ++p)
        s += (float)pacc[((size_t)p * NN + row) * EE + col] * ep[p];
    agg[(size_t)row * EE + col] = s / L;
}

// ---------------------------------------------------------------------------
// Kernel 3: out = relu(agg@wh1+bh1)@wh2 + bh2
// ---------------------------------------------------------------------------
__global__ __launch_bounds__(128) void k_head(
    const float* __restrict__ agg,
    const float* __restrict__ wh1, const float* __restrict__ bh1,
    const float* __restrict__ wh2, const float* __restrict__ bh2,
    float* __restrict__ out)
{
    __shared__ float ag[16][EE + 1];
    __shared__ float h2[16][EE + 1];
    const int t  = threadIdx.x;
    const int rg = t >> 4;
    const int ec = (t & 15) * 8;
    const int ra = rg * 2, rb = ra + 1;
    const int r0b = blockIdx.x * 16;

    #pragma unroll
    for (int r = 0; r < 16; ++r)
        ag[r][t] = agg[(size_t)(r0b + r) * EE + t];
    __syncthreads();
    {
        float a0[8], a1[8];
        #pragma unroll
        for (int j = 0; j < 8; ++j) { float b = bh1[ec + j]; a0[j] = b; a1[j] = b; }
        for (int s = 0; s < EE; ++s) {
            float x0 = ag[ra][s], x1 = ag[rb][s];
            const float* wrow = wh1 + s * EE + ec;
            #pragma unroll
            for (int j = 0; j < 8; ++j) { float w = wrow[j]; a0[j] = fmaf(x0, w, a0[j]); a1[j] = fmaf(x1, w, a1[j]); }
        }
        #pragma unroll
        for (int j = 0; j < 8; ++j) { h2[ra][ec + j] = fmaxf(a0[j], 0.f); h2[rb][ec + j] = fmaxf(a1[j], 0.f); }
    }
    __syncthreads();
    const int r = t >> 3, a = t & 7;
    float o = bh2[a];
    for (int s = 0; s < EE; ++s) o = fmaf(h2[r][s], wh2[s * AA + a], o);
    out[(size_t)(r0b + r) * AA + a] = o;
}

// ---------------------------------------------------------------------------
extern "C" void kernel_launch(void* const* d_in, const int* in_sizes, int n_in,
                              void* d_out, int out_size, void* d_ws, size_t ws_size,
                              hipStream_t stream)
{
    (void)in_sizes; (void)n_in; (void)out_size; (void)ws_size;
    const float* state = (const float*)d_in[0];
    const int*   adj   = (const int*)d_in[1];
    const float* w1  = (const float*)d_in[2];
    const float* b1  = (const float*)d_in[3];
    const float* w2  = (const float*)d_in[4];
    const float* b2  = (const float*)d_in[5];
    const float* wq  = (const float*)d_in[6];
    const float* wk  = (const float*)d_in[7];
    const float* wh1 = (const float*)d_in[8];
    const float* bh1 = (const float*)d_in[9];
    const float* wh2 = (const float*)d_in[10];
    const float* bh2 = (const float*)d_in[11];
    float* out = (float*)d_out;

    char* ws = (char*)d_ws;
    const size_t MB = 1024 * 1024;
    u16*      qb   = (u16*)ws;                       //  0..2 MB
    u16*      kb   = (u16*)(ws + 2 * MB);            //  2..4 MB
    u16*      hT   = (u16*)(ws + 4 * MB);            //  4..6 MB
    float*    agg  = (float*)(ws + 6 * MB);          //  6..10 MB
    u64*      msk  = (u64*)(ws + 10 * MB);           // 10..18 MB
    _Float16* pacc = (_Float16*)(ws + 18 * MB);      // 18..34 MB
    float*    pm   = (float*)(ws + 34 * MB);         // 34..34.25 MB
    float*    pl   = (float*)(ws + 34 * MB + 256 * 1024); // 34.25..34.5 MB

    k_mlp    <<<NN / 16, 128, 0, stream>>>(state, w1, b1, w2, b2, wq, wk, qb, kb, hT);
    k_adjmask<<<2048, 256, 0, stream>>>(adj, msk);
    k_attn   <<<(NN / 128) * NKVS, 256, 0, stream>>>(qb, kb, hT, msk, pacc, pm, pl);
    k_comb   <<<NN / 2, 256, 0, stream>>>(pacc, pm, pl, agg);
    k_head   <<<NN / 16, 128, 0, stream>>>(agg, wh1, bh1, wh2, bh2, out);
}